// Round 4
// baseline (1501.795 us; speedup 1.0000x reference)
//
#include <hip/hip_runtime.h>
#include <stdint.h>

typedef _Float16 f16;
typedef _Float16 f16x2 __attribute__((ext_vector_type(2)));
typedef _Float16 f16x8 __attribute__((ext_vector_type(8)));
typedef float f32x4 __attribute__((ext_vector_type(4)));

#define SEQ   512
#define BATCH 128
#define DIM   512
#define HID   256
#define G4    1024

typedef const __attribute__((address_space(1))) void* gas1p;
typedef __attribute__((address_space(3))) void* las3p;

__device__ __forceinline__ uint32_t pk2(float a, float b){
  return __builtin_bit_cast(uint32_t, __builtin_amdgcn_cvt_pkrtz(a, b));
}

__device__ __forceinline__ float fdot2u(uint32_t a, uint32_t b, float c){
#if __has_builtin(__builtin_amdgcn_fdot2)
  f16x2 A = __builtin_bit_cast(f16x2, a);
  f16x2 B = __builtin_bit_cast(f16x2, b);
  return __builtin_amdgcn_fdot2(A, B, c, false);
#else
  f16x2 A = __builtin_bit_cast(f16x2, a);
  f16x2 B = __builtin_bit_cast(f16x2, b);
  return c + (float)A.x*(float)B.x + (float)A.y*(float)B.y;
#endif
}

__device__ __forceinline__ float sigm(float x){
  return __builtin_amdgcn_rcpf(1.0f + __expf(-x));
}
__device__ __forceinline__ float tanh_(float x){
  return 1.0f - 2.0f*__builtin_amdgcn_rcpf(__expf(2.0f*x) + 1.0f);
}

// ---------------- phase 0: fp32 -> f16 convert (vectorized, 8 elems/thread) ----
__global__ void __launch_bounds__(256) cvt_f16_kernel(const float* __restrict__ in,
                                                      f16* __restrict__ out, int n8){
  int i = blockIdx.x*blockDim.x + threadIdx.x;
  if (i >= n8) return;
  const float4* p = (const float4*)in;
  float4 a = p[2*i], b = p[2*i+1];
  uint4 r;
  r.x = pk2(a.x, a.y); r.y = pk2(a.z, a.w);
  r.z = pk2(b.x, b.y); r.w = pk2(b.z, b.w);
  ((uint4*)out)[i] = r;
}

// ---------------- phase 0b: pack W_hh into f16 quads, layout [q][g] ------------
// Wq[q*1024 + g] = f16x8 of Whh[g][8q .. 8q+8), q = 0..31, g = 0..1023.
__global__ void __launch_bounds__(256) prep_whh(const float* __restrict__ Whh,
                                                uint4* __restrict__ Wq){
  int idx = blockIdx.x*256 + threadIdx.x;      // 0..32767
  int q = idx >> 10, g = idx & 1023;
  const float* wr = Whh + g*HID + 8*q;
  float4 v0 = *(const float4*)wr;
  float4 v1 = *(const float4*)(wr + 4);
  Wq[idx] = make_uint4(pk2(v0.x,v0.y), pk2(v0.z,v0.w), pk2(v1.x,v1.y), pk2(v1.z,v1.w));
}

// ---------------- phase 1: xg[m][g] = A[m][:] . W[g][:] + bias[g]  (f16 MFMA) --
#define BM 128
#define BN 128
#define BK 64

__global__ void __launch_bounds__(256) gemm_xg_kernel(const f16* __restrict__ A,
                                                      const f16* __restrict__ Bm,
                                                      const float* __restrict__ bih,
                                                      const float* __restrict__ bhh,
                                                      f16* __restrict__ C){
  __shared__ __align__(16) f16 ldsA[BM*BK];
  __shared__ __align__(16) f16 ldsB[BN*BK];
  const int tid  = threadIdx.x;
  const int wave = tid >> 6;
  const int lane = tid & 63;
  const int bid  = blockIdx.x;
  const int nt   = bid & 7;
  const int mt   = bid >> 3;
  const long m0  = (long)mt * BM;
  const int n0   = nt * BN;
  const int wm   = wave >> 1, wn = wave & 1;
  const int lrow = lane >> 3;
  const int lk   = (lane & 7) * 8;

  f32x4 acc[4][4];
  #pragma unroll
  for (int i=0;i<4;++i)
    #pragma unroll
    for (int j=0;j<4;++j) acc[i][j] = (f32x4){0.f,0.f,0.f,0.f};

  auto ldsAq = (__attribute__((address_space(3))) char*)ldsA;
  auto ldsBq = (__attribute__((address_space(3))) char*)ldsB;

  for (int kt = 0; kt < DIM/BK; ++kt){
    const int k0 = kt*BK;
    __syncthreads();
    #pragma unroll
    for (int i = 0; i < 4; ++i){
      const int seg = wave*4 + i;
      const f16* ga = A  + (m0 + seg*8 + lrow)*DIM + (k0 + lk);
      const f16* gb = Bm + (long)(n0 + seg*8 + lrow)*DIM + (k0 + lk);
      __builtin_amdgcn_global_load_lds((gas1p)ga, (las3p)(ldsAq + seg*1024), 16, 0, 0);
      __builtin_amdgcn_global_load_lds((gas1p)gb, (las3p)(ldsBq + seg*1024), 16, 0, 0);
    }
    __syncthreads();
    #pragma unroll
    for (int kk = 0; kk < 2; ++kk){
      f16x8 af[4], bf[4];
      const int kb = kk*32 + (lane>>4)*8;
      #pragma unroll
      for (int mi=0; mi<4; ++mi){
        af[mi] = *(const f16x8*)(ldsA + (wm*64 + mi*16 + (lane&15))*BK + kb);
        bf[mi] = *(const f16x8*)(ldsB + (wn*64 + mi*16 + (lane&15))*BK + kb);
      }
      #pragma unroll
      for (int mi=0;mi<4;++mi)
        #pragma unroll
        for (int ni=0;ni<4;++ni)
          acc[mi][ni] = __builtin_amdgcn_mfma_f32_16x16x32_f16(af[mi], bf[ni], acc[mi][ni], 0,0,0);
    }
  }
  float bias[4];
  #pragma unroll
  for (int ni=0;ni<4;++ni){
    int col = n0 + wn*64 + ni*16 + (lane&15);
    bias[ni] = bih[col] + bhh[col];
  }
  #pragma unroll
  for (int mi=0;mi<4;++mi){
    #pragma unroll
    for (int ni=0;ni<4;++ni){
      int col = n0 + wn*64 + ni*16 + (lane&15);
      #pragma unroll
      for (int r=0;r<4;++r){
        long row = m0 + wm*64 + mi*16 + (lane>>4)*4 + r;
        C[row*G4 + col] = (f16)(acc[mi][ni][r] + bias[ni]);
      }
    }
  }
}

// ---------------- phase 2: sequential LSTM + fused FC head ---------------------
// 128 blocks x 256 threads (4 waves = 1 wave/SIMD -> full 512-reg unified file).
// Thread j owns LSTM unit j: gate rows j (i), j+256 (f), j+512 (g), j+768 (o).
// No gate exchange; c,h local. h double-buffered in LDS, ONE barrier per step.
// Weights: k 0..31 in 64KB LDS, k 32..255 in 448 per-thread regs (arch+AGPR).
__global__ void __launch_bounds__(256)
__attribute__((amdgpu_waves_per_eu(1, 1)))
lstm_kernel(const f16* __restrict__ xg,
            const uint4* __restrict__ Wq,
            const float* __restrict__ fcw,
            const float* __restrict__ fcb,
            float* __restrict__ out){
  extern __shared__ __align__(16) char smem[];
  uint4* Wl4 = (uint4*)smem;                 // q 0..3: [q][1024] quads = 64 KiB
  f16*   hb  = (f16*)(smem + 65536);         // h double buffer: 2 x 256 f16
  float* red = (float*)(smem + 66560);       // 256 f32 reduce buffer
  const int j = threadIdx.x;
  const int b = blockIdx.x;

  // cooperative LDS fill: quads q=0..3 for all 1024 gate rows (linear copy)
  #pragma unroll
  for (int i = 0; i < 16; ++i) Wl4[i*256 + j] = Wq[i*256 + j];

  // register weights: q = 4..31 for this thread's 4 gate rows
  uint4 wr0[28], wr1[28], wr2[28], wr3[28];
  #pragma unroll
  for (int q = 4; q < 32; ++q) wr0[q-4] = Wq[q*1024 + j      ];
  #pragma unroll
  for (int q = 4; q < 32; ++q) wr1[q-4] = Wq[q*1024 + j + 256];
  #pragma unroll
  for (int q = 4; q < 32; ++q) wr2[q-4] = Wq[q*1024 + j + 512];
  #pragma unroll
  for (int q = 4; q < 32; ++q) wr3[q-4] = Wq[q*1024 + j + 768];

  hb[j] = (f16)0.f;                          // h buffer 0 = h_0 = 0
  float c = 0.f, hlast = 0.f;
  __syncthreads();

  const f16* xrow = xg + (long)b * SEQ * G4;
  f16 p0 = xrow[j], p1 = xrow[j+256], p2 = xrow[j+512], p3 = xrow[j+768];

  for (int ts = 0; ts < SEQ; ++ts){
    float a0 = (float)p0, a1 = (float)p1, a2 = (float)p2, a3 = (float)p3;
    if (ts + 1 < SEQ){                       // prefetch next step's xg
      const f16* xn = xrow + (ts+1)*G4;
      p0 = xn[j]; p1 = xn[j+256]; p2 = xn[j+512]; p3 = xn[j+768];
    }
    const uint4* hq = (const uint4*)(hb + (ts & 1)*256);  // 32 broadcast quads
    #pragma unroll
    for (int q = 0; q < 4; ++q){             // k 0..31 from LDS
      uint4 hv = hq[q];
      uint4 w0 = Wl4[q*1024 + j      ];
      uint4 w1 = Wl4[q*1024 + j + 256];
      uint4 w2 = Wl4[q*1024 + j + 512];
      uint4 w3 = Wl4[q*1024 + j + 768];
      a0 = fdot2u(w0.x,hv.x,a0); a0 = fdot2u(w0.y,hv.y,a0);
      a0 = fdot2u(w0.z,hv.z,a0); a0 = fdot2u(w0.w,hv.w,a0);
      a1 = fdot2u(w1.x,hv.x,a1); a1 = fdot2u(w1.y,hv.y,a1);
      a1 = fdot2u(w1.z,hv.z,a1); a1 = fdot2u(w1.w,hv.w,a1);
      a2 = fdot2u(w2.x,hv.x,a2); a2 = fdot2u(w2.y,hv.y,a2);
      a2 = fdot2u(w2.z,hv.z,a2); a2 = fdot2u(w2.w,hv.w,a2);
      a3 = fdot2u(w3.x,hv.x,a3); a3 = fdot2u(w3.y,hv.y,a3);
      a3 = fdot2u(w3.z,hv.z,a3); a3 = fdot2u(w3.w,hv.w,a3);
    }
    #pragma unroll
    for (int q = 4; q < 32; ++q){            // k 32..255 from registers
      uint4 hv = hq[q];
      const int o = q - 4;
      a0 = fdot2u(wr0[o].x,hv.x,a0); a0 = fdot2u(wr0[o].y,hv.y,a0);
      a0 = fdot2u(wr0[o].z,hv.z,a0); a0 = fdot2u(wr0[o].w,hv.w,a0);
      a1 = fdot2u(wr1[o].x,hv.x,a1); a1 = fdot2u(wr1[o].y,hv.y,a1);
      a1 = fdot2u(wr1[o].z,hv.z,a1); a1 = fdot2u(wr1[o].w,hv.w,a1);
      a2 = fdot2u(wr2[o].x,hv.x,a2); a2 = fdot2u(wr2[o].y,hv.y,a2);
      a2 = fdot2u(wr2[o].z,hv.z,a2); a2 = fdot2u(wr2[o].w,hv.w,a2);
      a3 = fdot2u(wr3[o].x,hv.x,a3); a3 = fdot2u(wr3[o].y,hv.y,a3);
      a3 = fdot2u(wr3[o].z,hv.z,a3); a3 = fdot2u(wr3[o].w,hv.w,a3);
    }
    float iv = sigm(a0), fv = sigm(a1), gv = tanh_(a2), ov = sigm(a3);
    c     = fv*c + iv*gv;
    hlast = ov * tanh_(c);
    hb[((ts+1) & 1)*256 + j] = (f16)hlast;   // publish h_{t+1} to other buffer
    __syncthreads();                         // one barrier per step
  }

  // ---- fused FC head: out[b] = h . fc_w + fc_b
  red[j] = hlast * fcw[j];
  __syncthreads();
  if (j < 64){
    float s = red[j] + red[j+64] + red[j+128] + red[j+192];
    #pragma unroll
    for (int off = 32; off; off >>= 1) s += __shfl_down(s, off);
    if (j == 0) out[b] = s + fcb[0];
  }
}

extern "C" void kernel_launch(void* const* d_in, const int* in_sizes, int n_in,
                              void* d_out, int out_size, void* d_ws, size_t ws_size,
                              hipStream_t stream) {
  const float* x   = (const float*)d_in[0];
  const float* Wih = (const float*)d_in[1];
  const float* Whh = (const float*)d_in[2];
  const float* bih = (const float*)d_in[3];
  const float* bhh = (const float*)d_in[4];
  const float* fcw = (const float*)d_in[5];
  const float* fcb = (const float*)d_in[6];
  float* out = (float*)d_out;

  char* ws = (char*)d_ws;
  f16*   xh  = (f16*)ws;                                   //  67,108,864 B
  f16*   Wh  = (f16*)(ws + 67108864);                      //   1,048,576 B
  f16*   xg  = (f16*)(ws + 68157440);                      // 134,217,728 B
  uint4* Wq  = (uint4*)(ws + 202375168);                   //     524,288 B

  cvt_f16_kernel<<<16384, 256, 0, stream>>>(x,   xh, 33554432/8);
  cvt_f16_kernel<<<256,   256, 0, stream>>>(Wih, Wh, 524288/8);
  prep_whh<<<128, 256, 0, stream>>>(Whh, Wq);
  gemm_xg_kernel<<<4096, 256, 0, stream>>>(xh, Wh, bih, bhh, xg);
  (void)hipFuncSetAttribute(reinterpret_cast<const void*>(lstm_kernel),
                            hipFuncAttributeMaxDynamicSharedMemorySize, 67584);
  lstm_kernel<<<BATCH, 256, 67584, stream>>>(xg, Wq, fcw, fcb, out);
}

// Round 5
// 781.076 us; speedup vs baseline: 1.9227x; 1.9227x over previous
//
#include <hip/hip_runtime.h>
#include <stdint.h>

typedef _Float16 f16;
typedef _Float16 f16x2 __attribute__((ext_vector_type(2)));
typedef _Float16 f16x8 __attribute__((ext_vector_type(8)));
typedef float f32x4 __attribute__((ext_vector_type(4)));

#define SEQ   512
#define BATCH 128
#define DIM   512
#define HID   256
#define G4    1024

typedef const __attribute__((address_space(1))) void* gas1p;
typedef __attribute__((address_space(3))) void* las3p;

__device__ __forceinline__ uint32_t pk2(float a, float b){
  return __builtin_bit_cast(uint32_t, __builtin_amdgcn_cvt_pkrtz(a, b));
}

__device__ __forceinline__ int sdot4(uint32_t a, uint32_t b, int c){
#if __has_builtin(__builtin_amdgcn_sdot4)
  return __builtin_amdgcn_sdot4(a, b, c, false);
#else
  int s = c;
  #pragma unroll
  for (int i = 0; i < 4; ++i){
    int ai = (int)(signed char)((a >> (8*i)) & 0xff);
    int bi = (int)(signed char)((b >> (8*i)) & 0xff);
    s += ai*bi;
  }
  return s;
#endif
}

__device__ __forceinline__ float sigm(float x){
  return __builtin_amdgcn_rcpf(1.0f + __expf(-x));
}
__device__ __forceinline__ float tanh_(float x){
  return 1.0f - 2.0f*__builtin_amdgcn_rcpf(__expf(2.0f*x) + 1.0f);
}

// ---------------- phase 0: fp32 -> f16 convert (vectorized, 8 elems/thread) ----
__global__ void __launch_bounds__(256) cvt_f16_kernel(const float* __restrict__ in,
                                                      f16* __restrict__ out, int n8){
  int i = blockIdx.x*blockDim.x + threadIdx.x;
  if (i >= n8) return;
  const float4* p = (const float4*)in;
  float4 a = p[2*i], b = p[2*i+1];
  uint4 r;
  r.x = pk2(a.x, a.y); r.y = pk2(a.z, a.w);
  r.z = pk2(b.x, b.y); r.w = pk2(b.z, b.w);
  ((uint4*)out)[i] = r;
}

// ---------------- phase 0b: quantize W_hh to i8 (scale 2048), per-thread layout -
// Output word p (0..65535): lstm-thread t = p>>7, row r = (p>>5)&3, qq = p&31.
// gate row g = (t&255) + r*256; k-u32 index kw = (t>>8)*32 + qq.
// W8L[p] packs Whh[g][4kw..4kw+4) as 4 signed i8.
__global__ void __launch_bounds__(256) prep_whh8(const float* __restrict__ Whh,
                                                 uint32_t* __restrict__ W8L){
  int p = blockIdx.x*256 + threadIdx.x;        // 0..65535
  int t  = p >> 7;
  int r  = (p >> 5) & 3;
  int qq = p & 31;
  int g  = (t & 255) + (r << 8);
  int kw = ((t >> 8) << 5) + qq;
  float4 v = *(const float4*)(Whh + g*HID + kw*4);
  int a = __float2int_rn(v.x*2048.f); a = a > 127 ? 127 : (a < -127 ? -127 : a);
  int b = __float2int_rn(v.y*2048.f); b = b > 127 ? 127 : (b < -127 ? -127 : b);
  int c = __float2int_rn(v.z*2048.f); c = c > 127 ? 127 : (c < -127 ? -127 : c);
  int d = __float2int_rn(v.w*2048.f); d = d > 127 ? 127 : (d < -127 ? -127 : d);
  W8L[p] = (uint32_t)(a & 0xff) | ((uint32_t)(b & 0xff) << 8) |
           ((uint32_t)(c & 0xff) << 16) | ((uint32_t)(d & 0xff) << 24);
}

// ---------------- phase 1: xg = x . W_ih^T + bias, f16 MFMA --------------------
// Epilogue writes QUAD layout: for gate col g, unit u=g&255, type tau=g>>8:
// C[m*1024 + u*4 + tau]  (so each unit's {i,f,g,o} are contiguous f16x4).
#define BM 128
#define BN 128
#define BK 64

__global__ void __launch_bounds__(256) gemm_xg_kernel(const f16* __restrict__ A,
                                                      const f16* __restrict__ Bm,
                                                      const float* __restrict__ bih,
                                                      const float* __restrict__ bhh,
                                                      f16* __restrict__ C){
  __shared__ __align__(16) f16 ldsA[BM*BK];
  __shared__ __align__(16) f16 ldsB[BN*BK];
  const int tid  = threadIdx.x;
  const int wave = tid >> 6;
  const int lane = tid & 63;
  const int bid  = blockIdx.x;
  const int nt   = bid & 7;
  const int mt   = bid >> 3;
  const long m0  = (long)mt * BM;
  const int n0   = nt * BN;
  const int wm   = wave >> 1, wn = wave & 1;
  const int lrow = lane >> 3;
  const int lk   = (lane & 7) * 8;

  f32x4 acc[4][4];
  #pragma unroll
  for (int i=0;i<4;++i)
    #pragma unroll
    for (int j=0;j<4;++j) acc[i][j] = (f32x4){0.f,0.f,0.f,0.f};

  auto ldsAq = (__attribute__((address_space(3))) char*)ldsA;
  auto ldsBq = (__attribute__((address_space(3))) char*)ldsB;

  for (int kt = 0; kt < DIM/BK; ++kt){
    const int k0 = kt*BK;
    __syncthreads();
    #pragma unroll
    for (int i = 0; i < 4; ++i){
      const int seg = wave*4 + i;
      const f16* ga = A  + (m0 + seg*8 + lrow)*DIM + (k0 + lk);
      const f16* gb = Bm + (long)(n0 + seg*8 + lrow)*DIM + (k0 + lk);
      __builtin_amdgcn_global_load_lds((gas1p)ga, (las3p)(ldsAq + seg*1024), 16, 0, 0);
      __builtin_amdgcn_global_load_lds((gas1p)gb, (las3p)(ldsBq + seg*1024), 16, 0, 0);
    }
    __syncthreads();
    #pragma unroll
    for (int kk = 0; kk < 2; ++kk){
      f16x8 af[4], bf[4];
      const int kb = kk*32 + (lane>>4)*8;
      #pragma unroll
      for (int mi=0; mi<4; ++mi){
        af[mi] = *(const f16x8*)(ldsA + (wm*64 + mi*16 + (lane&15))*BK + kb);
        bf[mi] = *(const f16x8*)(ldsB + (wn*64 + mi*16 + (lane&15))*BK + kb);
      }
      #pragma unroll
      for (int mi=0;mi<4;++mi)
        #pragma unroll
        for (int ni=0;ni<4;++ni)
          acc[mi][ni] = __builtin_amdgcn_mfma_f32_16x16x32_f16(af[mi], bf[ni], acc[mi][ni], 0,0,0);
    }
  }
  float bias[4];
  #pragma unroll
  for (int ni=0;ni<4;++ni){
    int col = n0 + wn*64 + ni*16 + (lane&15);
    bias[ni] = bih[col] + bhh[col];
  }
  #pragma unroll
  for (int mi=0;mi<4;++mi){
    #pragma unroll
    for (int ni=0;ni<4;++ni){
      int col = n0 + wn*64 + ni*16 + (lane&15);
      int cpos = (col & 255)*4 + (col >> 8);       // quad layout
      #pragma unroll
      for (int r=0;r<4;++r){
        long row = m0 + wm*64 + mi*16 + (lane>>4)*4 + r;
        C[row*G4 + cpos] = (f16)(acc[mi][ni][r] + bias[ni]);
      }
    }
  }
}

// ---------------- phase 2: sequential LSTM (i8 dot4) + fused FC head -----------
// 128 blocks x 512 threads (8 waves, 2/SIMD). Thread t: unit j=t&255, k-half
// kap=t>>8. Weights: 4 gate rows x 128 k as 128 u32 i8-quads, ALL in VGPRs.
// h: i8[2][256] LDS double buffer (wave-uniform b128 reads). Partial gate sums
// exchanged as exact i32 via LDS. kap=0 threads do activations + h-quant.
__global__ void __launch_bounds__(512) lstm8_kernel(const f16* __restrict__ xq,
                                                    const uint32_t* __restrict__ W8L,
                                                    const float* __restrict__ fcw,
                                                    const float* __restrict__ fcb,
                                                    float* __restrict__ out){
  __shared__ __align__(16) uint8_t h8[2][256];
  __shared__ __align__(16) int4  part[256];
  __shared__ float red[256];
  const int t = threadIdx.x;
  const int b = blockIdx.x;
  const int j = t & 255;
  const int kap = t >> 8;
  const float invS = 1.0f / (2048.0f * 127.0f);

  // per-thread weights: 512 B contiguous
  uint32_t w[4][32];
  {
    const uint4* wp = (const uint4*)(W8L + t*128);
    #pragma unroll
    for (int r = 0; r < 4; ++r)
      #pragma unroll
      for (int q8 = 0; q8 < 8; ++q8){
        uint4 u = wp[r*8 + q8];
        w[r][q8*4+0] = u.x; w[r][q8*4+1] = u.y;
        w[r][q8*4+2] = u.z; w[r][q8*4+3] = u.w;
      }
  }
  if (t < 128) ((uint32_t*)h8)[t] = 0;       // zero both h buffers

  const f16* xrow = xq + (long)b * SEQ * G4;
  ushort4 xv = make_ushort4(0,0,0,0);
  if (kap == 0) xv = *(const ushort4*)(xrow + j*4);
  float c = 0.f, hlast = 0.f;
  __syncthreads();

  for (int ts = 0; ts < SEQ; ++ts){
    const uint4* hq = (const uint4*)&h8[ts & 1][kap*128];  // wave-uniform
    int a0=0,b0=0, a1=0,b1=0, a2=0,b2=0, a3=0,b3=0;        // 8 chains for ILP
    #pragma unroll
    for (int q = 0; q < 8; q += 2){
      uint4 h0 = hq[q], h1 = hq[q+1];
      a0 = sdot4(w[0][q*4+0],h0.x,a0); a0 = sdot4(w[0][q*4+1],h0.y,a0);
      a0 = sdot4(w[0][q*4+2],h0.z,a0); a0 = sdot4(w[0][q*4+3],h0.w,a0);
      b0 = sdot4(w[0][q*4+4],h1.x,b0); b0 = sdot4(w[0][q*4+5],h1.y,b0);
      b0 = sdot4(w[0][q*4+6],h1.z,b0); b0 = sdot4(w[0][q*4+7],h1.w,b0);
      a1 = sdot4(w[1][q*4+0],h0.x,a1); a1 = sdot4(w[1][q*4+1],h0.y,a1);
      a1 = sdot4(w[1][q*4+2],h0.z,a1); a1 = sdot4(w[1][q*4+3],h0.w,a1);
      b1 = sdot4(w[1][q*4+4],h1.x,b1); b1 = sdot4(w[1][q*4+5],h1.y,b1);
      b1 = sdot4(w[1][q*4+6],h1.z,b1); b1 = sdot4(w[1][q*4+7],h1.w,b1);
      a2 = sdot4(w[2][q*4+0],h0.x,a2); a2 = sdot4(w[2][q*4+1],h0.y,a2);
      a2 = sdot4(w[2][q*4+2],h0.z,a2); a2 = sdot4(w[2][q*4+3],h0.w,a2);
      b2 = sdot4(w[2][q*4+4],h1.x,b2); b2 = sdot4(w[2][q*4+5],h1.y,b2);
      b2 = sdot4(w[2][q*4+6],h1.z,b2); b2 = sdot4(w[2][q*4+7],h1.w,b2);
      a3 = sdot4(w[3][q*4+0],h0.x,a3); a3 = sdot4(w[3][q*4+1],h0.y,a3);
      a3 = sdot4(w[3][q*4+2],h0.z,a3); a3 = sdot4(w[3][q*4+3],h0.w,a3);
      b3 = sdot4(w[3][q*4+4],h1.x,b3); b3 = sdot4(w[3][q*4+5],h1.y,b3);
      b3 = sdot4(w[3][q*4+6],h1.z,b3); b3 = sdot4(w[3][q*4+7],h1.w,b3);
    }
    a0 += b0; a1 += b1; a2 += b2; a3 += b3;
    if (kap == 1) part[j] = make_int4(a0, a1, a2, a3);
    __syncthreads();
    if (kap == 0){
      int4 p = part[j];
      f16 xi = __builtin_bit_cast(f16, xv.x), xf = __builtin_bit_cast(f16, xv.y);
      f16 xg_ = __builtin_bit_cast(f16, xv.z), xo = __builtin_bit_cast(f16, xv.w);
      float gi = (float)xi + (float)(a0 + p.x)*invS;
      float gf = (float)xf + (float)(a1 + p.y)*invS;
      float gg = (float)xg_ + (float)(a2 + p.z)*invS;
      float go = (float)xo + (float)(a3 + p.w)*invS;
      if (ts + 1 < SEQ) xv = *(const ushort4*)(xrow + (ts+1)*G4 + j*4);
      float iv = sigm(gi), fv = sigm(gf), gv = tanh_(gg), ov = sigm(go);
      c     = fv*c + iv*gv;
      hlast = ov * tanh_(c);
      int hq8 = __float2int_rn(hlast * 127.f);
      h8[(ts+1) & 1][j] = (uint8_t)(hq8 & 0xff);
    }
    __syncthreads();
  }

  // ---- fused FC head
  if (kap == 0) red[j] = hlast * fcw[j];
  __syncthreads();
  if (t < 64){
    float s = red[t] + red[t+64] + red[t+128] + red[t+192];
    #pragma unroll
    for (int off = 32; off; off >>= 1) s += __shfl_down(s, off);
    if (t == 0) out[b] = s + fcb[0];
  }
}

extern "C" void kernel_launch(void* const* d_in, const int* in_sizes, int n_in,
                              void* d_out, int out_size, void* d_ws, size_t ws_size,
                              hipStream_t stream) {
  const float* x   = (const float*)d_in[0];
  const float* Wih = (const float*)d_in[1];
  const float* Whh = (const float*)d_in[2];
  const float* bih = (const float*)d_in[3];
  const float* bhh = (const float*)d_in[4];
  const float* fcw = (const float*)d_in[5];
  const float* fcb = (const float*)d_in[6];
  float* out = (float*)d_out;

  char* ws = (char*)d_ws;
  f16*      xh  = (f16*)ws;                                //  67,108,864 B
  f16*      Wh  = (f16*)(ws + 67108864);                   //   1,048,576 B
  f16*      xq  = (f16*)(ws + 68157440);                   // 134,217,728 B
  uint32_t* W8L = (uint32_t*)(ws + 202375168);             //     262,144 B

  cvt_f16_kernel<<<16384, 256, 0, stream>>>(x,   xh, 33554432/8);
  cvt_f16_kernel<<<256,   256, 0, stream>>>(Wih, Wh, 524288/8);
  prep_whh8<<<256, 256, 0, stream>>>(Whh, W8L);
  gemm_xg_kernel<<<4096, 256, 0, stream>>>(xh, Wh, bih, bhh, xq);
  lstm8_kernel<<<BATCH, 512, 0, stream>>>(xq, W8L, fcw, fcb, out);
}

// Round 6
// 693.519 us; speedup vs baseline: 2.1655x; 1.1263x over previous
//
#include <hip/hip_runtime.h>
#include <stdint.h>

typedef _Float16 f16;
typedef _Float16 f16x2 __attribute__((ext_vector_type(2)));
typedef _Float16 f16x8 __attribute__((ext_vector_type(8)));
typedef float f32x4 __attribute__((ext_vector_type(4)));

#define SEQ   512
#define BATCH 128
#define DIM   512
#define HID   256
#define G4    1024

typedef const __attribute__((address_space(1))) void* gas1p;
typedef __attribute__((address_space(3))) void* las3p;

__device__ __forceinline__ uint32_t pk2(float a, float b){
  return __builtin_bit_cast(uint32_t, __builtin_amdgcn_cvt_pkrtz(a, b));
}

__device__ __forceinline__ int sdot4(uint32_t a, uint32_t b, int c){
#if __has_builtin(__builtin_amdgcn_sdot4)
  return __builtin_amdgcn_sdot4(a, b, c, false);
#else
  int s = c;
  #pragma unroll
  for (int i = 0; i < 4; ++i){
    int ai = (int)(signed char)((a >> (8*i)) & 0xff);
    int bi = (int)(signed char)((b >> (8*i)) & 0xff);
    s += ai*bi;
  }
  return s;
#endif
}

__device__ __forceinline__ float sigm(float x){
  return __builtin_amdgcn_rcpf(1.0f + __expf(-x));
}
__device__ __forceinline__ float tanh_(float x){
  return 1.0f - 2.0f*__builtin_amdgcn_rcpf(__expf(2.0f*x) + 1.0f);
}

// ---------------- phase 0: fp32 -> f16 convert (vectorized, 8 elems/thread) ----
__global__ void __launch_bounds__(256) cvt_f16_kernel(const float* __restrict__ in,
                                                      f16* __restrict__ out, int n8){
  int i = blockIdx.x*blockDim.x + threadIdx.x;
  if (i >= n8) return;
  const float4* p = (const float4*)in;
  float4 a = p[2*i], b = p[2*i+1];
  uint4 r;
  r.x = pk2(a.x, a.y); r.y = pk2(a.z, a.w);
  r.z = pk2(b.x, b.y); r.w = pk2(b.z, b.w);
  ((uint4*)out)[i] = r;
}

// ---------------- phase 0b: quantize W_hh to i8 (scale 2048), per-thread layout -
// Word p (0..65535): lstm-thread t = p>>7, row r = (p>>5)&3, qq = p&31.
// Thread t: wave = t>>6, lane = t&63, unit j = wave*32 + (lane&31),
// k-half = (t>>5)&1. Gate row g = j + r*256; k-u32 kw = khalf*32 + qq.
// W8L[p] packs Whh[g][4kw..4kw+4) as 4 signed i8 (w[r*32+qq] of thread t).
__global__ void __launch_bounds__(256) prep_whh8(const float* __restrict__ Whh,
                                                 uint32_t* __restrict__ W8L){
  int p = blockIdx.x*256 + threadIdx.x;        // 0..65535
  int t  = p >> 7;
  int r  = (p >> 5) & 3;
  int qq = p & 31;
  int lane  = t & 63;
  int j     = (t >> 6)*32 + (lane & 31);
  int khalf = (lane >> 5) & 1;
  int g  = j + (r << 8);
  int kw = khalf*32 + qq;
  float4 v = *(const float4*)(Whh + g*HID + kw*4);
  int a = __float2int_rn(v.x*2048.f); a = a > 127 ? 127 : (a < -127 ? -127 : a);
  int b = __float2int_rn(v.y*2048.f); b = b > 127 ? 127 : (b < -127 ? -127 : b);
  int c = __float2int_rn(v.z*2048.f); c = c > 127 ? 127 : (c < -127 ? -127 : c);
  int d = __float2int_rn(v.w*2048.f); d = d > 127 ? 127 : (d < -127 ? -127 : d);
  W8L[p] = (uint32_t)(a & 0xff) | ((uint32_t)(b & 0xff) << 8) |
           ((uint32_t)(c & 0xff) << 16) | ((uint32_t)(d & 0xff) << 24);
}

// ---------------- phase 1: xg = x . W_ih^T + bias, f16 MFMA --------------------
// Epilogue writes QUAD layout: for gate col g, unit u=g&255, type tau=g>>8:
// C[m*1024 + u*4 + tau]  (so each unit's {i,f,g,o} are contiguous f16x4).
#define BM 128
#define BN 128
#define BK 64

__global__ void __launch_bounds__(256) gemm_xg_kernel(const f16* __restrict__ A,
                                                      const f16* __restrict__ Bm,
                                                      const float* __restrict__ bih,
                                                      const float* __restrict__ bhh,
                                                      f16* __restrict__ C){
  __shared__ __align__(16) f16 ldsA[BM*BK];
  __shared__ __align__(16) f16 ldsB[BN*BK];
  const int tid  = threadIdx.x;
  const int wave = tid >> 6;
  const int lane = tid & 63;
  const int bid  = blockIdx.x;
  const int nt   = bid & 7;
  const int mt   = bid >> 3;
  const long m0  = (long)mt * BM;
  const int n0   = nt * BN;
  const int wm   = wave >> 1, wn = wave & 1;
  const int lrow = lane >> 3;
  const int lk   = (lane & 7) * 8;

  f32x4 acc[4][4];
  #pragma unroll
  for (int i=0;i<4;++i)
    #pragma unroll
    for (int j=0;j<4;++j) acc[i][j] = (f32x4){0.f,0.f,0.f,0.f};

  auto ldsAq = (__attribute__((address_space(3))) char*)ldsA;
  auto ldsBq = (__attribute__((address_space(3))) char*)ldsB;

  for (int kt = 0; kt < DIM/BK; ++kt){
    const int k0 = kt*BK;
    __syncthreads();
    #pragma unroll
    for (int i = 0; i < 4; ++i){
      const int seg = wave*4 + i;
      const f16* ga = A  + (m0 + seg*8 + lrow)*DIM + (k0 + lk);
      const f16* gb = Bm + (long)(n0 + seg*8 + lrow)*DIM + (k0 + lk);
      __builtin_amdgcn_global_load_lds((gas1p)ga, (las3p)(ldsAq + seg*1024), 16, 0, 0);
      __builtin_amdgcn_global_load_lds((gas1p)gb, (las3p)(ldsBq + seg*1024), 16, 0, 0);
    }
    __syncthreads();
    #pragma unroll
    for (int kk = 0; kk < 2; ++kk){
      f16x8 af[4], bf[4];
      const int kb = kk*32 + (lane>>4)*8;
      #pragma unroll
      for (int mi=0; mi<4; ++mi){
        af[mi] = *(const f16x8*)(ldsA + (wm*64 + mi*16 + (lane&15))*BK + kb);
        bf[mi] = *(const f16x8*)(ldsB + (wn*64 + mi*16 + (lane&15))*BK + kb);
      }
      #pragma unroll
      for (int mi=0;mi<4;++mi)
        #pragma unroll
        for (int ni=0;ni<4;++ni)
          acc[mi][ni] = __builtin_amdgcn_mfma_f32_16x16x32_f16(af[mi], bf[ni], acc[mi][ni], 0,0,0);
    }
  }
  float bias[4];
  #pragma unroll
  for (int ni=0;ni<4;++ni){
    int col = n0 + wn*64 + ni*16 + (lane&15);
    bias[ni] = bih[col] + bhh[col];
  }
  #pragma unroll
  for (int mi=0;mi<4;++mi){
    #pragma unroll
    for (int ni=0;ni<4;++ni){
      int col = n0 + wn*64 + ni*16 + (lane&15);
      int cpos = (col & 255)*4 + (col >> 8);       // quad layout
      #pragma unroll
      for (int r=0;r<4;++r){
        long row = m0 + wm*64 + mi*16 + (lane>>4)*4 + r;
        C[row*G4 + cpos] = (f16)(acc[mi][ni][r] + bias[ni]);
      }
    }
  }
}

// ---------------- phase 2: sequential LSTM (i8 dot4) + fused FC head -----------
// 128 blocks x 512 threads (8 waves = 2/SIMD, 1 block/CU). Lanes l and l^32 of
// wave w share unit j = w*32 + (l&31); each holds one k-half (128 k) of all 4
// gate rows as 128 u32 i8-quads PINNED in VGPRs (asm keep-alive). Partial sums
// exchanged via __shfl_xor(32) (no barrier); activations duplicated by both
// halves; ONE __syncthreads per step. h: i8[2][256] LDS double buffer.
__global__ void __launch_bounds__(512)
__attribute__((amdgpu_waves_per_eu(2, 2)))
lstm8_kernel(const f16* __restrict__ xq,
             const uint32_t* __restrict__ W8L,
             const float* __restrict__ fcw,
             const float* __restrict__ fcb,
             float* __restrict__ out){
  __shared__ __align__(16) uint8_t h8[2][256];
  __shared__ float red[256];
  const int t = threadIdx.x;
  const int b = blockIdx.x;
  const int lane  = t & 63;
  const int j     = (t >> 6)*32 + (lane & 31);
  const int khalf = lane >> 5;
  const float invS = 1.0f / (2048.0f * 127.0f);

  // per-thread weights: 512 B contiguous; force into VGPRs
  uint32_t w[128];
  {
    const uint4* wp = (const uint4*)(W8L + (size_t)t*128);
    #pragma unroll
    for (int q8 = 0; q8 < 32; ++q8){
      uint4 u = wp[q8];
      w[4*q8+0] = u.x; w[4*q8+1] = u.y; w[4*q8+2] = u.z; w[4*q8+3] = u.w;
    }
  }
  #pragma unroll
  for (int i = 0; i < 128; ++i) asm volatile("" : "+v"(w[i]));

  if (t < 128) ((uint32_t*)h8)[t] = 0;         // zero both h buffers

  const f16* xrow = xq + (long)b * SEQ * G4;
  ushort4 xv = *(const ushort4*)(xrow + j*4);  // step-0 gate quad {i,f,g,o}
  float c = 0.f, hlast = 0.f;
  __syncthreads();

  for (int ts = 0; ts < SEQ; ++ts){
    const uint4* hq = (const uint4*)&h8[ts & 1][khalf*128];
    uint4 hv[8];
    #pragma unroll
    for (int q = 0; q < 8; ++q) hv[q] = hq[q];  // 2-addr broadcast reads (free)

    int acc[4];
    #pragma unroll
    for (int r = 0; r < 4; ++r){
      int a = 0, bb = 0;                        // 2 chains per row for ILP
      #pragma unroll
      for (int q = 0; q < 4; ++q){
        a = sdot4(w[r*32+4*q+0], hv[q].x, a);
        a = sdot4(w[r*32+4*q+1], hv[q].y, a);
        a = sdot4(w[r*32+4*q+2], hv[q].z, a);
        a = sdot4(w[r*32+4*q+3], hv[q].w, a);
      }
      #pragma unroll
      for (int q = 4; q < 8; ++q){
        bb = sdot4(w[r*32+4*q+0], hv[q].x, bb);
        bb = sdot4(w[r*32+4*q+1], hv[q].y, bb);
        bb = sdot4(w[r*32+4*q+2], hv[q].z, bb);
        bb = sdot4(w[r*32+4*q+3], hv[q].w, bb);
      }
      acc[r] = a + bb;
    }
    // combine the two k-halves within the wave (lanes l <-> l^32), no barrier
    #pragma unroll
    for (int r = 0; r < 4; ++r) acc[r] += __shfl_xor(acc[r], 32);

    // activations (both halves compute identically)
    f16 xi  = __builtin_bit_cast(f16, xv.x), xf = __builtin_bit_cast(f16, xv.y);
    f16 xg_ = __builtin_bit_cast(f16, xv.z), xo = __builtin_bit_cast(f16, xv.w);
    float gi = (float)xi  + (float)acc[0]*invS;
    float gf = (float)xf  + (float)acc[1]*invS;
    float gg = (float)xg_ + (float)acc[2]*invS;
    float go = (float)xo  + (float)acc[3]*invS;
    if (ts + 1 < SEQ) xv = *(const ushort4*)(xrow + (ts+1)*G4 + j*4);
    float iv = sigm(gi), fv = sigm(gf), gv = tanh_(gg), ov = sigm(go);
    c     = fv*c + iv*gv;
    hlast = ov * tanh_(c);
    int hq8 = __float2int_rn(hlast * 127.f);
    if (khalf == 0) h8[(ts+1) & 1][j] = (uint8_t)(hq8 & 0xff);
    __syncthreads();                            // ONE barrier per step
  }

  // ---- fused FC head
  if (khalf == 0) red[j] = hlast * fcw[j];
  __syncthreads();
  if (t < 64){
    float s = red[t] + red[t+64] + red[t+128] + red[t+192];
    #pragma unroll
    for (int off = 32; off; off >>= 1) s += __shfl_down(s, off);
    if (t == 0) out[b] = s + fcb[0];
  }
}

extern "C" void kernel_launch(void* const* d_in, const int* in_sizes, int n_in,
                              void* d_out, int out_size, void* d_ws, size_t ws_size,
                              hipStream_t stream) {
  const float* x   = (const float*)d_in[0];
  const float* Wih = (const float*)d_in[1];
  const float* Whh = (const float*)d_in[2];
  const float* bih = (const float*)d_in[3];
  const float* bhh = (const float*)d_in[4];
  const float* fcw = (const float*)d_in[5];
  const float* fcb = (const float*)d_in[6];
  float* out = (float*)d_out;

  char* ws = (char*)d_ws;
  f16*      xh  = (f16*)ws;                                //  67,108,864 B
  f16*      Wh  = (f16*)(ws + 67108864);                   //   1,048,576 B
  f16*      xq  = (f16*)(ws + 68157440);                   // 134,217,728 B
  uint32_t* W8L = (uint32_t*)(ws + 202375168);             //     262,144 B

  cvt_f16_kernel<<<16384, 256, 0, stream>>>(x,   xh, 33554432/8);
  cvt_f16_kernel<<<256,   256, 0, stream>>>(Wih, Wh, 524288/8);
  prep_whh8<<<256, 256, 0, stream>>>(Whh, W8L);
  gemm_xg_kernel<<<4096, 256, 0, stream>>>(xh, Wh, bih, bhh, xq);
  lstm8_kernel<<<BATCH, 512, 0, stream>>>(xq, W8L, fcw, fcb, out);
}

// Round 7
// 661.675 us; speedup vs baseline: 2.2697x; 1.0481x over previous
//
#include <hip/hip_runtime.h>
#include <stdint.h>

typedef _Float16 f16;
typedef _Float16 f16x2 __attribute__((ext_vector_type(2)));
typedef _Float16 f16x8 __attribute__((ext_vector_type(8)));
typedef float f32x4 __attribute__((ext_vector_type(4)));

#define SEQ   512
#define BATCH 128
#define DIM   512
#define HID   256
#define G4    1024

typedef const __attribute__((address_space(1))) void* gas1p;
typedef __attribute__((address_space(3))) void* las3p;

__device__ __forceinline__ uint32_t pk2(float a, float b){
  return __builtin_bit_cast(uint32_t, __builtin_amdgcn_cvt_pkrtz(a, b));
}

__device__ __forceinline__ int sdot4(uint32_t a, uint32_t b, int c){
#if __has_builtin(__builtin_amdgcn_sdot4)
  return __builtin_amdgcn_sdot4(a, b, c, false);
#else
  int s = c;
  #pragma unroll
  for (int i = 0; i < 4; ++i){
    int ai = (int)(signed char)((a >> (8*i)) & 0xff);
    int bi = (int)(signed char)((b >> (8*i)) & 0xff);
    s += ai*bi;
  }
  return s;
#endif
}

__device__ __forceinline__ float sigm(float x){
  return __builtin_amdgcn_rcpf(1.0f + __expf(-x));
}
__device__ __forceinline__ float tanh_(float x){
  return 1.0f - 2.0f*__builtin_amdgcn_rcpf(__expf(2.0f*x) + 1.0f);
}

// ---------------- phase 0: fp32 -> f16 convert (vectorized, 8 elems/thread) ----
__global__ void __launch_bounds__(256) cvt_f16_kernel(const float* __restrict__ in,
                                                      f16* __restrict__ out, int n8){
  int i = blockIdx.x*blockDim.x + threadIdx.x;
  if (i >= n8) return;
  const float4* p = (const float4*)in;
  float4 a = p[2*i], b = p[2*i+1];
  uint4 r;
  r.x = pk2(a.x, a.y); r.y = pk2(a.z, a.w);
  r.z = pk2(b.x, b.y); r.w = pk2(b.z, b.w);
  ((uint4*)out)[i] = r;
}

// ---------------- phase 0b: quantize W_hh to i8 (scale 2048), per-thread layout -
// Word p (0..65535): lstm-thread t = p>>7, row r = (p>>5)&3, qq = p&31.
// Thread t: wave = t>>6, lane = t&63, unit j = wave*32 + (lane&31),
// k-half = (t>>5)&1. Gate row g = j + r*256; k-u32 kw = khalf*32 + qq.
__global__ void __launch_bounds__(256) prep_whh8(const float* __restrict__ Whh,
                                                 uint32_t* __restrict__ W8L){
  int p = blockIdx.x*256 + threadIdx.x;        // 0..65535
  int t  = p >> 7;
  int r  = (p >> 5) & 3;
  int qq = p & 31;
  int lane  = t & 63;
  int j     = (t >> 6)*32 + (lane & 31);
  int khalf = (lane >> 5) & 1;
  int g  = j + (r << 8);
  int kw = khalf*32 + qq;
  float4 v = *(const float4*)(Whh + g*HID + kw*4);
  int a = __float2int_rn(v.x*2048.f); a = a > 127 ? 127 : (a < -127 ? -127 : a);
  int b = __float2int_rn(v.y*2048.f); b = b > 127 ? 127 : (b < -127 ? -127 : b);
  int c = __float2int_rn(v.z*2048.f); c = c > 127 ? 127 : (c < -127 ? -127 : c);
  int d = __float2int_rn(v.w*2048.f); d = d > 127 ? 127 : (d < -127 ? -127 : d);
  W8L[p] = (uint32_t)(a & 0xff) | ((uint32_t)(b & 0xff) << 8) |
           ((uint32_t)(c & 0xff) << 16) | ((uint32_t)(d & 0xff) << 24);
}

// ---------------- phase 1: xg = x . W_ih^T + bias, f16 MFMA --------------------
// Epilogue writes QUAD layout: for gate col g, unit u=g&255, type tau=g>>8:
// C[m*1024 + u*4 + tau]  (so each unit's {i,f,g,o} are contiguous f16x4).
#define BM 128
#define BN 128
#define BK 64

__global__ void __launch_bounds__(256) gemm_xg_kernel(const f16* __restrict__ A,
                                                      const f16* __restrict__ Bm,
                                                      const float* __restrict__ bih,
                                                      const float* __restrict__ bhh,
                                                      f16* __restrict__ C){
  __shared__ __align__(16) f16 ldsA[BM*BK];
  __shared__ __align__(16) f16 ldsB[BN*BK];
  const int tid  = threadIdx.x;
  const int wave = tid >> 6;
  const int lane = tid & 63;
  const int bid  = blockIdx.x;
  const int nt   = bid & 7;
  const int mt   = bid >> 3;
  const long m0  = (long)mt * BM;
  const int n0   = nt * BN;
  const int wm   = wave >> 1, wn = wave & 1;
  const int lrow = lane >> 3;
  const int lk   = (lane & 7) * 8;

  f32x4 acc[4][4];
  #pragma unroll
  for (int i=0;i<4;++i)
    #pragma unroll
    for (int j=0;j<4;++j) acc[i][j] = (f32x4){0.f,0.f,0.f,0.f};

  auto ldsAq = (__attribute__((address_space(3))) char*)ldsA;
  auto ldsBq = (__attribute__((address_space(3))) char*)ldsB;

  for (int kt = 0; kt < DIM/BK; ++kt){
    const int k0 = kt*BK;
    __syncthreads();
    #pragma unroll
    for (int i = 0; i < 4; ++i){
      const int seg = wave*4 + i;
      const f16* ga = A  + (m0 + seg*8 + lrow)*DIM + (k0 + lk);
      const f16* gb = Bm + (long)(n0 + seg*8 + lrow)*DIM + (k0 + lk);
      __builtin_amdgcn_global_load_lds((gas1p)ga, (las3p)(ldsAq + seg*1024), 16, 0, 0);
      __builtin_amdgcn_global_load_lds((gas1p)gb, (las3p)(ldsBq + seg*1024), 16, 0, 0);
    }
    __syncthreads();
    #pragma unroll
    for (int kk = 0; kk < 2; ++kk){
      f16x8 af[4], bf[4];
      const int kb = kk*32 + (lane>>4)*8;
      #pragma unroll
      for (int mi=0; mi<4; ++mi){
        af[mi] = *(const f16x8*)(ldsA + (wm*64 + mi*16 + (lane&15))*BK + kb);
        bf[mi] = *(const f16x8*)(ldsB + (wn*64 + mi*16 + (lane&15))*BK + kb);
      }
      #pragma unroll
      for (int mi=0;mi<4;++mi)
        #pragma unroll
        for (int ni=0;ni<4;++ni)
          acc[mi][ni] = __builtin_amdgcn_mfma_f32_16x16x32_f16(af[mi], bf[ni], acc[mi][ni], 0,0,0);
    }
  }
  float bias[4];
  #pragma unroll
  for (int ni=0;ni<4;++ni){
    int col = n0 + wn*64 + ni*16 + (lane&15);
    bias[ni] = bih[col] + bhh[col];
  }
  #pragma unroll
  for (int mi=0;mi<4;++mi){
    #pragma unroll
    for (int ni=0;ni<4;++ni){
      int col = n0 + wn*64 + ni*16 + (lane&15);
      int cpos = (col & 255)*4 + (col >> 8);       // quad layout
      #pragma unroll
      for (int r=0;r<4;++r){
        long row = m0 + wm*64 + mi*16 + (lane>>4)*4 + r;
        C[row*G4 + cpos] = (f16)(acc[mi][ni][r] + bias[ni]);
      }
    }
  }
}

// ---------------- phase 2: sequential LSTM (i8 dot4) + fused FC head -----------
// 128 blocks x 512 threads (8 waves = 2/SIMD, 1 block/CU). Lanes l and l^32 of
// wave w share unit j = w*32 + (l&31); each holds one k-half (128 k) of all 4
// gate rows as 128 u32 i8-quads in VGPRs. NO __launch_bounds__ (it pins RA to a
// high-occupancy budget); r4-proven attribute combo instead -> 256-reg budget,
// pressure ~185, no spill. Partials combined via __shfl_xor(32); ONE barrier
// per step; h: i8[2][256] LDS double buffer (2-address broadcast reads).
__global__ void
__attribute__((amdgpu_flat_work_group_size(512, 512), amdgpu_waves_per_eu(2, 2)))
lstm8_kernel(const f16* __restrict__ xq,
             const uint32_t* __restrict__ W8L,
             const float* __restrict__ fcw,
             const float* __restrict__ fcb,
             float* __restrict__ out){
  __shared__ __align__(16) uint8_t h8[2][256];
  __shared__ float red[256];
  const int t = threadIdx.x;
  const int b = blockIdx.x;
  const int lane  = t & 63;
  const int j     = (t >> 6)*32 + (lane & 31);
  const int khalf = lane >> 5;
  const float invS = 1.0f / (2048.0f * 127.0f);

  // per-thread weights: 512 B contiguous; keep-alive pins them as live values
  uint32_t w[128];
  {
    const uint4* wp = (const uint4*)(W8L + (size_t)t*128);
    #pragma unroll
    for (int q8 = 0; q8 < 32; ++q8){
      uint4 u = wp[q8];
      w[4*q8+0] = u.x; w[4*q8+1] = u.y; w[4*q8+2] = u.z; w[4*q8+3] = u.w;
    }
  }
  #pragma unroll
  for (int i = 0; i < 128; ++i) asm volatile("" : "+v"(w[i]));

  if (t < 128) ((uint32_t*)h8)[t] = 0;         // zero both h buffers

  const f16* xrow = xq + (long)b * SEQ * G4;
  ushort4 xv = *(const ushort4*)(xrow + j*4);  // step-0 gate quad {i,f,g,o}
  float c = 0.f, hlast = 0.f;
  __syncthreads();

  for (int ts = 0; ts < SEQ; ++ts){
    // consume current xv; issue next-step prefetch IMMEDIATELY (full-step cover)
    ushort4 xc = xv;
    if (ts + 1 < SEQ) xv = *(const ushort4*)(xrow + (ts+1)*G4 + j*4);

    const uint4* hq = (const uint4*)&h8[ts & 1][khalf*128];
    uint4 hv[8];
    #pragma unroll
    for (int q = 0; q < 8; ++q) hv[q] = hq[q];  // 2-addr broadcast reads

    int acc[4] = {0, 0, 0, 0};
    #pragma unroll
    for (int q = 0; q < 8; ++q){                // q-major: 4 indep chains (rows)
      #pragma unroll
      for (int r = 0; r < 4; ++r){
        acc[r] = sdot4(w[r*32+4*q+0], hv[q].x, acc[r]);
        acc[r] = sdot4(w[r*32+4*q+1], hv[q].y, acc[r]);
        acc[r] = sdot4(w[r*32+4*q+2], hv[q].z, acc[r]);
        acc[r] = sdot4(w[r*32+4*q+3], hv[q].w, acc[r]);
      }
    }
    // combine the two k-halves within the wave (lanes l <-> l^32), no barrier
    #pragma unroll
    for (int r = 0; r < 4; ++r) acc[r] += __shfl_xor(acc[r], 32);

    // activations (both halves compute identically)
    f16 xi  = __builtin_bit_cast(f16, xc.x), xf = __builtin_bit_cast(f16, xc.y);
    f16 xg_ = __builtin_bit_cast(f16, xc.z), xo = __builtin_bit_cast(f16, xc.w);
    float gi = (float)xi  + (float)acc[0]*invS;
    float gf = (float)xf  + (float)acc[1]*invS;
    float gg = (float)xg_ + (float)acc[2]*invS;
    float go = (float)xo  + (float)acc[3]*invS;
    float iv = sigm(gi), fv = sigm(gf), gv = tanh_(gg), ov = sigm(go);
    c     = fv*c + iv*gv;
    hlast = ov * tanh_(c);
    int hq8 = __float2int_rn(hlast * 127.f);
    if (khalf == 0) h8[(ts+1) & 1][j] = (uint8_t)(hq8 & 0xff);
    __syncthreads();                            // ONE barrier per step
  }

  // ---- fused FC head
  if (khalf == 0) red[j] = hlast * fcw[j];
  __syncthreads();
  if (t < 64){
    float s = red[t] + red[t+64] + red[t+128] + red[t+192];
    #pragma unroll
    for (int off = 32; off; off >>= 1) s += __shfl_down(s, off);
    if (t == 0) out[b] = s + fcb[0];
  }
}

extern "C" void kernel_launch(void* const* d_in, const int* in_sizes, int n_in,
                              void* d_out, int out_size, void* d_ws, size_t ws_size,
                              hipStream_t stream) {
  const float* x   = (const float*)d_in[0];
  const float* Wih = (const float*)d_in[1];
  const float* Whh = (const float*)d_in[2];
  const float* bih = (const float*)d_in[3];
  const float* bhh = (const float*)d_in[4];
  const float* fcw = (const float*)d_in[5];
  const float* fcb = (const float*)d_in[6];
  float* out = (float*)d_out;

  char* ws = (char*)d_ws;
  f16*      xh  = (f16*)ws;                                //  67,108,864 B
  f16*      Wh  = (f16*)(ws + 67108864);                   //   1,048,576 B
  f16*      xq  = (f16*)(ws + 68157440);                   // 134,217,728 B
  uint32_t* W8L = (uint32_t*)(ws + 202375168);             //     262,144 B

  cvt_f16_kernel<<<16384, 256, 0, stream>>>(x,   xh, 33554432/8);
  cvt_f16_kernel<<<256,   256, 0, stream>>>(Wih, Wh, 524288/8);
  prep_whh8<<<256, 256, 0, stream>>>(Whh, W8L);
  gemm_xg_kernel<<<4096, 256, 0, stream>>>(xh, Wh, bih, bhh, xq);
  lstm8_kernel<<<BATCH, 512, 0, stream>>>(xq, W8L, fcw, fcb, out);
}